// Round 18
// baseline (351.708 us; speedup 1.0000x reference)
//
#include <hip/hip_runtime.h>
#include <hip/hip_bf16.h>
#include <hip/hip_fp16.h>

#define N_NODES 100000
#define N_EDGES 3200000
#define ET (N_EDGES + N_NODES)   // edges + self loops
#define F_IN 500
#define H1 8
#define C1 8
#define F1 64                    // H1*C1
#define C2 7

#define BSH 6                    // 64 nodes per bucket
#define NB ((N_NODES + 63) / 64) // 1563
#define CAP2 4096                // LDS sorted-edge capacity per bucket (avg ~2111)
#define FB 128                   // partition blocks
#define FCHUNK ((ET + FB - 1) / FB)

typedef __attribute__((ext_vector_type(8))) short short8;
typedef __attribute__((ext_vector_type(4))) float f32x4;

__device__ __forceinline__ unsigned short f2bf(float f) {
    const unsigned u = __float_as_uint(f);
    return (unsigned short)((u + 0x7FFFu + ((u >> 16) & 1u)) >> 16);
}

// ---------------- CSR build: atomic-free 3-phase partition ----------------
__global__ __launch_bounds__(1024) void fill_count(const int* __restrict__ ei,
                                                   int* __restrict__ cntmat) {
    __shared__ int hist[NB];
    const int t = threadIdx.x, blk = blockIdx.x;
    for (int i = t; i < NB; i += 1024) hist[i] = 0;
    __syncthreads();
    const int s0 = blk * FCHUNK;
    const int s1 = min(s0 + FCHUNK, ET);
    for (int i = s0 + t; i < s1; i += 1024) {
        const int dst = (i < N_EDGES) ? ei[N_EDGES + i] : (i - N_EDGES);
        atomicAdd(&hist[dst >> BSH], 1);
    }
    __syncthreads();
    int* row = cntmat + (size_t)blk * NB;
    for (int i = t; i < NB; i += 1024) row[i] = hist[i];
}

// single block: bucket totals -> exclusive scan -> boff, bexcl
__global__ __launch_bounds__(1024) void scan2a(const int* __restrict__ cntmat,
                                               int* __restrict__ boff,
                                               int* __restrict__ bexcl) {
    __shared__ int tot[2048];
    __shared__ int wsum[16];
    const int t = threadIdx.x;
    const int lane = t & 63;
    const int w = t >> 6;
    for (int b = t; b < 2048; b += 1024) {
        int s = 0;
        if (b < NB)
            for (int j = 0; j < FB; ++j) s += cntmat[(size_t)j * NB + b];
        tot[b] = s;
    }
    __syncthreads();
    int running = 0;
    for (int t0 = 0; t0 < 2048; t0 += 1024) {
        const int v = tot[t0 + t];
        int sc = v;
#pragma unroll
        for (int d = 1; d < 64; d <<= 1) {
            int u = __shfl_up(sc, d);
            if (lane >= d) sc += u;
        }
        if (lane == 63) wsum[w] = sc;
        __syncthreads();
        if (t < 16) {
            int ws = wsum[t];
#pragma unroll
            for (int d = 1; d < 16; d <<= 1) {
                int u = __shfl_up(ws, d);
                if (t >= d) ws += u;
            }
            wsum[t] = ws;
        }
        __syncthreads();
        const int excl = running + (w ? wsum[w - 1] : 0) + sc - v;
        if (t0 + t < NB) {
            boff[t0 + t] = excl;
            bexcl[t0 + t] = excl;
        }
        const int tt = wsum[15];
        __syncthreads();
        running += tt;
    }
    if (t == 0) boff[NB] = running;     // == ET
}

// parallel per-column scan over blocks: basemat[j][b] = bexcl[b] + prefix_j
__global__ __launch_bounds__(256) void scan2b(const int* __restrict__ cntmat,
                                              const int* __restrict__ bexcl,
                                              int* __restrict__ basemat) {
    const int b = blockIdx.x * 256 + threadIdx.x;
    if (b >= NB) return;
    int run = bexcl[b];
#pragma unroll 4
    for (int j = 0; j < FB; ++j) {
        basemat[(size_t)j * NB + b] = run;
        run += cntmat[(size_t)j * NB + b];
    }
}

__global__ __launch_bounds__(1024) void fill_scatter(const int* __restrict__ ei,
                                                     const int* __restrict__ basemat,
                                                     unsigned int* __restrict__ ebuf) {
    __shared__ int cur[NB];
    const int t = threadIdx.x, blk = blockIdx.x;
    const int* row = basemat + (size_t)blk * NB;
    for (int i = t; i < NB; i += 1024) cur[i] = row[i];
    __syncthreads();
    const int s0 = blk * FCHUNK;
    const int s1 = min(s0 + FCHUNK, ET);
    for (int i = s0 + t; i < s1; i += 1024) {
        int src, dst;
        if (i < N_EDGES) { src = ei[i]; dst = ei[N_EDGES + i]; }
        else             { src = dst = i - N_EDGES; }
        const int b = dst >> BSH;
        const int p = atomicAdd(&cur[b], 1);
        ebuf[p] = (unsigned)src | ((unsigned)(dst & 63) << 17);
    }
}

// ---------------- W prep: W1[500][64] -> bf16 fragment-packed wpk ----------------
__global__ __launch_bounds__(256) void wprep(const float* __restrict__ W1,
                                             short* __restrict__ wpk) {
    const int idx = blockIdx.x * 256 + threadIdx.x;
    if (idx >= 32768) return;
    const int j = idx & 7;
    const int l = (idx >> 3) & 63;
    const int f = (idx >> 9) & 3;
    const int ks = idx >> 11;
    const int k = ks * 32 + ((l >> 4) << 3) + j;
    const int col = f * 16 + (l & 15);
    const float fv = (k < F_IN) ? W1[k * F1 + col] : 0.f;
    wpk[idx] = (short)f2bf(fv);
}

// ---------------- layer 1 GEMM: MFMA, LDS-staged coalesced A (XOR-swizzled) ----
// Chunks of k=64 staged into xs[2][64][64] (32 KB). Staging: flat-linear
// coalesced float4 global reads, ds_write at unit seg^(row&7). Frag reads:
// lane reads units (2q)^e, (2q|1)^e of its row -> 8-way-even banks (b128 min).
__global__ __launch_bounds__(256) void gemm1_kernel(
    const float* __restrict__ x, const short* __restrict__ wpk,
    const float* __restrict__ a_src, const float* __restrict__ a_dst,
    __half* __restrict__ h1, float* __restrict__ as1, float* __restrict__ ad1)
{
    __shared__ float xs[2][4096];
    const int t = threadIdx.x;
    const int l = t & 63;
    const int w = t >> 6;
    const int row0 = blockIdx.x * 64;
    // staging mapping: slot = i*256 + t -> row = i*16 + (t>>4), seg = t&15
    const int srow = t >> 4;
    const int sseg = t & 15;
    // frag read mapping
    const int r = l & 15, q = l >> 4;
    const int myrow = w * 16 + r;
    const int e = myrow & 7;
    const int offA = myrow * 64 + (((q * 2) ^ e) << 2);
    const int offB = myrow * 64 + ((((q * 2) | 1) ^ e) << 2);
    const short* __restrict__ wl = wpk + (l << 3);
    const size_t maxidx = (size_t)N_NODES * F_IN - 4;

    const int rg0 = min(row0 + srow, N_NODES - 1);
    const int rg1 = min(row0 + 16 + srow, N_NODES - 1);
    const int rg2 = min(row0 + 32 + srow, N_NODES - 1);
    const int rg3 = min(row0 + 48 + srow, N_NODES - 1);
    const int wseg0 = (sseg ^ (srow & 7)) << 2;
    const int wseg1 = (sseg ^ ((16 + srow) & 7)) << 2;
    const int wseg2 = (sseg ^ ((32 + srow) & 7)) << 2;
    const int wseg3 = (sseg ^ ((48 + srow) & 7)) << 2;

    f32x4 acc[4];
#pragma unroll
    for (int f = 0; f < 4; ++f) acc[f] = (f32x4){0.f, 0.f, 0.f, 0.f};

    float4 stg0, stg1, stg2, stg3;
    // preload chunk 0
    {
        const int k0 = 0;
        stg0 = *(const float4*)(x + min((size_t)rg0 * F_IN + k0 + sseg * 4, maxidx));
        stg1 = *(const float4*)(x + min((size_t)rg1 * F_IN + k0 + sseg * 4, maxidx));
        stg2 = *(const float4*)(x + min((size_t)rg2 * F_IN + k0 + sseg * 4, maxidx));
        stg3 = *(const float4*)(x + min((size_t)rg3 * F_IN + k0 + sseg * 4, maxidx));
    }

    for (int c = 0; c < 8; ++c) {
        float* buf = xs[c & 1];
        // write staged chunk c (swizzled dest)
        *(float4*)&buf[(srow)      * 64 + wseg0] = stg0;
        *(float4*)&buf[(16 + srow) * 64 + wseg1] = stg1;
        *(float4*)&buf[(32 + srow) * 64 + wseg2] = stg2;
        *(float4*)&buf[(48 + srow) * 64 + wseg3] = stg3;
        // issue chunk c+1 global loads (land during compute)
        if (c < 7) {
            const int k0 = (c + 1) * 64;
            stg0 = *(const float4*)(x + min((size_t)rg0 * F_IN + k0 + sseg * 4, maxidx));
            stg1 = *(const float4*)(x + min((size_t)rg1 * F_IN + k0 + sseg * 4, maxidx));
            stg2 = *(const float4*)(x + min((size_t)rg2 * F_IN + k0 + sseg * 4, maxidx));
            stg3 = *(const float4*)(x + min((size_t)rg3 * F_IN + k0 + sseg * 4, maxidx));
        }
        __syncthreads();
#pragma unroll
        for (int ksub = 0; ksub < 2; ++ksub) {
            const float4 va = *(const float4*)&buf[offA + ksub * 32];
            const float4 vb = *(const float4*)&buf[offB + ksub * 32];
            float v[8];
            v[0] = va.x; v[1] = va.y; v[2] = va.z; v[3] = va.w;
            v[4] = vb.x; v[5] = vb.y; v[6] = vb.z; v[7] = vb.w;
            short8 ah, al;
#pragma unroll
            for (int j = 0; j < 8; ++j) {
                const unsigned short h = f2bf(v[j]);
                ah[j] = (short)h;
                al[j] = (short)f2bf(v[j] - __uint_as_float((unsigned)h << 16));
            }
            const int ks = c * 2 + ksub;
#pragma unroll
            for (int f = 0; f < 4; ++f) {
                const short8 bh = *(const short8*)(wl + ((ks * 4 + f) << 9));
                acc[f] = __builtin_amdgcn_mfma_f32_16x16x32_bf16(ah, bh, acc[f], 0, 0, 0);
                acc[f] = __builtin_amdgcn_mfma_f32_16x16x32_bf16(al, bh, acc[f], 0, 0, 0);
            }
        }
    }

    // epilogue: D[row][col], row = row0 + w*16 + (l>>4)*4 + reg, col = f*16 + (l&15)
    const int g = l >> 4;
    const int p = r >> 3;
    float asv[4], adv[4];
#pragma unroll
    for (int f = 0; f < 4; ++f) {
        asv[f] = a_src[f * 16 + r];
        adv[f] = a_dst[f * 16 + r];
    }
#pragma unroll
    for (int f = 0; f < 4; ++f) {
#pragma unroll
        for (int reg = 0; reg < 4; ++reg) {
            const int row = row0 + w * 16 + g * 4 + reg;
            const float hv = acc[f][reg];
            if (row < N_NODES)
                h1[(size_t)row * F1 + f * 16 + r] = __float2half(hv);
            float ps = hv * asv[f];
            float pd = hv * adv[f];
            ps += __shfl_xor(ps, 1); ps += __shfl_xor(ps, 2); ps += __shfl_xor(ps, 4);
            pd += __shfl_xor(pd, 1); pd += __shfl_xor(pd, 2); pd += __shfl_xor(pd, 4);
            if ((l & 7) == 0 && row < N_NODES) {
                as1[row * H1 + f * 2 + p] = ps;
                ad1[row * H1 + f * 2 + p] = pd;
            }
        }
    }
}

// ---------------- layer 1 agg: in-LDS sort + register accum; persists sort ----
__global__ __launch_bounds__(256) void agg1_kernel(
    const int* __restrict__ boff, const unsigned int* __restrict__ ebuf,
    const __half* __restrict__ h1, const float* __restrict__ as1,
    const float* __restrict__ ad1, const float* __restrict__ b1,
    __half* __restrict__ hout, int* __restrict__ colidx,
    int* __restrict__ rowptrg)
{
    __shared__ int colb[CAP2];
    __shared__ int hist[64], curs[64], rowp[65];
    const int t = threadIdx.x, b = blockIdx.x;
    const int e0 = boff[b];
    const int cnt = boff[b + 1] - e0;
    const int l = t & 63;
    const int w = t >> 6;
    if (t < 64) hist[t] = 0;
    __syncthreads();

    if (cnt <= CAP2) {
        for (int i = t; i < cnt; i += 256)
            atomicAdd(&hist[ebuf[e0 + i] >> 17], 1);
        __syncthreads();
        if (t < 64) {
            const int v = hist[t];
            int sc = v;
#pragma unroll
            for (int d = 1; d < 64; d <<= 1) {
                int u = __shfl_up(sc, d);
                if (t >= d) sc += u;
            }
            rowp[t] = sc - v;
            curs[t] = sc - v;
            if (t == 63) rowp[64] = sc;
        }
        __syncthreads();
        for (int i = t; i < cnt; i += 256) {
            const unsigned v = ebuf[e0 + i];
            const int p = atomicAdd(&curs[v >> 17], 1);
            colb[p] = (int)(v & 0x1FFFFu);
        }
        __syncthreads();
        // persist sorted CSR for agg2 (coalesced)
        for (int i = t; i < cnt; i += 256) colidx[e0 + i] = colb[i];
        if (t < 65) rowptrg[b * 65 + t] = e0 + rowp[t];

        const int jsub = l & 7;
        const int hsub = l >> 3;
        const int pbase = l & 56;
        for (int ni = 0; ni < 16; ++ni) {
            const int d = w * 16 + ni;
            const int n = (b << 6) + d;
            if (n >= N_NODES) break;            // wave-uniform
            const int rr0 = rowp[d], rr1 = rowp[d + 1];
            const float adh = ad1[(n << 3) + hsub];
            float den = 0.f, acc = 0.f;
            int j0 = rr0;
            for (; j0 + 8 <= rr1; j0 += 8) {
                const int s_l = colb[j0 + jsub];
                float e = as1[(s_l << 3) + hsub] + adh;
                e = fmaxf(e, 0.2f * e);
                const float p_l = __expf(e);
#pragma unroll
                for (int j = 0; j < 8; ++j) {
                    const float p = __shfl(p_l, pbase + j);
                    const int s_j = __builtin_amdgcn_readlane(s_l, j);
                    const float v = __half2float(h1[((size_t)(unsigned)s_j << 6) + l]);
                    den += p;
                    acc = fmaf(p, v, acc);
                }
            }
            if (j0 < rr1) {
                const int s_l = colb[min(j0 + jsub, rr1 - 1)];
                float e = as1[(s_l << 3) + hsub] + adh;
                e = fmaxf(e, 0.2f * e);
                const float p_l = __expf(e);
#pragma unroll
                for (int j = 0; j < 8; ++j) {
                    if (j0 + j < rr1) {
                        const float p = __shfl(p_l, pbase + j);
                        const int s_j = __builtin_amdgcn_readlane(s_l, j);
                        const float v = __half2float(h1[((size_t)(unsigned)s_j << 6) + l]);
                        den += p;
                        acc = fmaf(p, v, acc);
                    }
                }
            }
            hout[((size_t)n << 6) + l] = __float2half(acc / den + b1[l]);
        }
    } else {
        // fallback (statistically never): predicated full-bucket scan per node
        const int hsub = l >> 3;
        for (int ni = 0; ni < 16; ++ni) {
            const int d = w * 16 + ni;
            const int n = (b << 6) + d;
            if (n >= N_NODES) break;
            const float adh = ad1[(n << 3) + hsub];
            float den = 0.f, acc = 0.f;
            for (int i = 0; i < cnt; ++i) {
                const unsigned v = ebuf[e0 + i];
                if ((int)(v >> 17) == d) {
                    const int s = (int)(v & 0x1FFFFu);
                    float e = as1[(s << 3) + hsub] + adh;
                    e = fmaxf(e, 0.2f * e);
                    const float p = __expf(e);
                    const float hv = __half2float(h1[((size_t)s << 6) + l]);
                    den += p;
                    acc = fmaf(p, hv, acc);
                }
            }
            hout[((size_t)n << 6) + l] = __float2half(acc / den + b1[l]);
        }
    }
}

// ---------------- layer 2 GEMM (fp16 input) + attention coefficients ----------
__global__ __launch_bounds__(256) void gemm2_kernel(
    const __half* __restrict__ hin, const float* __restrict__ W2,
    const float* __restrict__ a_src, const float* __restrict__ a_dst,
    float* __restrict__ h2p, float* __restrict__ as2, float* __restrict__ ad2)
{
    __shared__ float w2s[F1 * C2];
    __shared__ float as_s[C2], ad_s[C2];
    for (int i = threadIdx.x; i < F1 * C2; i += blockDim.x) w2s[i] = W2[i];
    if (threadIdx.x < C2) { as_s[threadIdx.x] = a_src[threadIdx.x]; ad_s[threadIdx.x] = a_dst[threadIdx.x]; }
    __syncthreads();

    int n = blockIdx.x * blockDim.x + threadIdx.x;
    if (n >= N_NODES) return;
    float acc[C2];
#pragma unroll
    for (int c = 0; c < C2; ++c) acc[c] = 0.f;
    const short8* hp = (const short8*)(hin + ((size_t)n << 6));
#pragma unroll
    for (int k8 = 0; k8 < 8; ++k8) {
        const short8 h8 = hp[k8];
#pragma unroll
        for (int e = 0; e < 8; ++e) {
            const float hv = __half2float(__ushort_as_half((unsigned short)h8[e]));
            const int k = k8 * 8 + e;
#pragma unroll
            for (int c = 0; c < C2; ++c)
                acc[c] = fmaf(hv, w2s[k * C2 + c], acc[c]);
        }
    }
    float s = 0.f, d = 0.f;
#pragma unroll
    for (int c = 0; c < C2; ++c) {
        s = fmaf(acc[c], as_s[c], s);
        d = fmaf(acc[c], ad_s[c], d);
    }
    float4* o = (float4*)(h2p + (size_t)n * 8);
    o[0] = make_float4(acc[0], acc[1], acc[2], acc[3]);
    o[1] = make_float4(acc[4], acc[5], acc[6], 0.f);
    as2[n] = s;
    ad2[n] = d;
}

// ---------------- layer 2 agg: pre-sorted CSR, no LDS, quarter-wave ----------
__global__ __launch_bounds__(256) void agg2_kernel(
    const int* __restrict__ boff, const unsigned int* __restrict__ ebuf,
    const int* __restrict__ rowptrg, const int* __restrict__ colidx,
    const float* __restrict__ h2p, const float* __restrict__ as2,
    const float* __restrict__ ad2, const float* __restrict__ b2,
    float* __restrict__ out)
{
    const int t = threadIdx.x, b = blockIdx.x;
    const int d = t >> 2;             // node-in-bucket
    const int q = t & 3;
    const int n = (b << 6) + d;
    if (n >= N_NODES) return;
    const int cnt = boff[b + 1] - boff[b];
    const float adn = ad2[n];

    float denom = 0.f;
    float a0 = 0, a1 = 0, a2 = 0, a3 = 0, a4 = 0, a5 = 0, a6 = 0;
    if (cnt <= CAP2) {
        const int rr0 = rowptrg[b * 65 + d], rr1 = rowptrg[b * 65 + d + 1];
        for (int j = rr0 + q; j < rr1; j += 4) {
            const int s = colidx[j];
            float e = as2[s] + adn;
            e = fmaxf(e, 0.2f * e);
            const float ex = __expf(e);
            const float4 va = *(const float4*)(h2p + (size_t)s * 8);
            const float4 vb = *(const float4*)(h2p + (size_t)s * 8 + 4);
            denom += ex;
            a0 = fmaf(ex, va.x, a0); a1 = fmaf(ex, va.y, a1);
            a2 = fmaf(ex, va.z, a2); a3 = fmaf(ex, va.w, a3);
            a4 = fmaf(ex, vb.x, a4); a5 = fmaf(ex, vb.y, a5);
            a6 = fmaf(ex, vb.z, a6);
        }
    } else {
        // fallback (statistically never): predicated full-bucket scan
        const int e0 = boff[b];
        for (int i = q; i < cnt; i += 4) {
            const unsigned v = ebuf[e0 + i];
            if ((int)(v >> 17) == d) {
                const int s = (int)(v & 0x1FFFFu);
                float e = as2[s] + adn;
                e = fmaxf(e, 0.2f * e);
                const float ex = __expf(e);
                const float4 va = *(const float4*)(h2p + (size_t)s * 8);
                const float4 vb = *(const float4*)(h2p + (size_t)s * 8 + 4);
                denom += ex;
                a0 = fmaf(ex, va.x, a0); a1 = fmaf(ex, va.y, a1);
                a2 = fmaf(ex, va.z, a2); a3 = fmaf(ex, va.w, a3);
                a4 = fmaf(ex, vb.x, a4); a5 = fmaf(ex, vb.y, a5);
                a6 = fmaf(ex, vb.z, a6);
            }
        }
    }
#pragma unroll
    for (int dd = 1; dd < 4; dd <<= 1) {
        denom += __shfl_xor(denom, dd);
        a0 += __shfl_xor(a0, dd); a1 += __shfl_xor(a1, dd);
        a2 += __shfl_xor(a2, dd); a3 += __shfl_xor(a3, dd);
        a4 += __shfl_xor(a4, dd); a5 += __shfl_xor(a5, dd);
        a6 += __shfl_xor(a6, dd);
    }
    const float inv = 1.f / denom;
    float v0 = a0 * inv + b2[0], v1 = a1 * inv + b2[1];
    float v2 = a2 * inv + b2[2], v3 = a3 * inv + b2[3];
    float v4 = a4 * inv + b2[4], v5 = a5 * inv + b2[5];
    float v6 = a6 * inv + b2[6];
    float mx = fmaxf(fmaxf(fmaxf(v0, v1), fmaxf(v2, v3)), fmaxf(fmaxf(v4, v5), v6));
    const float se = __expf(v0 - mx) + __expf(v1 - mx) + __expf(v2 - mx) +
                     __expf(v3 - mx) + __expf(v4 - mx) + __expf(v5 - mx) +
                     __expf(v6 - mx);
    const float lse = __logf(se) + mx;
    const float wa = (q == 0) ? v0 : (q == 1) ? v1 : (q == 2) ? v2 : v3;
    const float wb = (q == 0) ? v4 : (q == 1) ? v5 : v6;
    out[n * C2 + q] = wa - lse;
    if (q < 3) out[n * C2 + q + 4] = wb - lse;
}

extern "C" void kernel_launch(void* const* d_in, const int* in_sizes, int n_in,
                              void* d_out, int out_size, void* d_ws, size_t ws_size,
                              hipStream_t stream) {
    const float* x      = (const float*)d_in[0];
    const int*   ei     = (const int*)  d_in[1];
    const float* W1     = (const float*)d_in[2];
    const float* a_src1 = (const float*)d_in[3];
    const float* a_dst1 = (const float*)d_in[4];
    const float* b1     = (const float*)d_in[5];
    const float* W2     = (const float*)d_in[6];
    const float* a_src2 = (const float*)d_in[7];
    const float* a_dst2 = (const float*)d_in[8];
    const float* b2     = (const float*)d_in[9];
    float* out = (float*)d_out;

    char* ws = (char*)d_ws;
    size_t off = 0;
    auto alloc = [&](size_t bytes) -> void* {
        void* p = ws + off;
        off += (bytes + 255) & ~(size_t)255;
        return p;
    };
    int*          boff    = (int*)   alloc((size_t)(NB + 1) * sizeof(int));
    int*          bexcl   = (int*)   alloc((size_t)NB * sizeof(int));
    int*          cntmat  = (int*)   alloc((size_t)FB * NB * sizeof(int));
    int*          basemat = (int*)   alloc((size_t)FB * NB * sizeof(int));
    unsigned int* ebuf    = (unsigned int*)alloc((size_t)ET * sizeof(unsigned int));
    int*          colidx  = (int*)   alloc((size_t)ET * sizeof(int));
    int*          rowptrg = (int*)   alloc((size_t)NB * 65 * sizeof(int));
    short*        wpk     = (short*) alloc((size_t)32768 * sizeof(short));
    __half*       h1      = (__half*)alloc((size_t)N_NODES * F1 * sizeof(__half));
    float*        as1     = (float*) alloc((size_t)N_NODES * H1 * sizeof(float));
    float*        ad1     = (float*) alloc((size_t)N_NODES * H1 * sizeof(float));
    __half*       hout1   = (__half*)alloc((size_t)N_NODES * F1 * sizeof(__half));
    float*        h2p     = (float*) alloc((size_t)N_NODES * 8 * sizeof(float));
    float*        as2     = (float*) alloc((size_t)N_NODES * sizeof(float));
    float*        ad2     = (float*) alloc((size_t)N_NODES * sizeof(float));

    wprep<<<128, 256, 0, stream>>>(W1, wpk);
    fill_count<<<FB, 1024, 0, stream>>>(ei, cntmat);
    scan2a<<<1, 1024, 0, stream>>>(cntmat, boff, bexcl);
    scan2b<<<(NB + 255) / 256, 256, 0, stream>>>(cntmat, bexcl, basemat);
    fill_scatter<<<FB, 1024, 0, stream>>>(ei, basemat, ebuf);
    gemm1_kernel<<<(N_NODES + 63) / 64, 256, 0, stream>>>(x, wpk, a_src1, a_dst1, h1, as1, ad1);
    agg1_kernel<<<NB, 256, 0, stream>>>(boff, ebuf, h1, as1, ad1, b1, hout1, colidx, rowptrg);
    gemm2_kernel<<<(N_NODES + 255) / 256, 256, 0, stream>>>(hout1, W2, a_src2, a_dst2, h2p, as2, ad2);
    agg2_kernel<<<NB, 256, 0, stream>>>(boff, ebuf, rowptrg, colidx, h2p, as2, ad2, b2, out);
}

// Round 19
// 333.864 us; speedup vs baseline: 1.0534x; 1.0534x over previous
//
#include <hip/hip_runtime.h>
#include <hip/hip_bf16.h>
#include <hip/hip_fp16.h>

#define N_NODES 100000
#define N_EDGES 3200000
#define ET (N_EDGES + N_NODES)   // edges + self loops
#define F_IN 500
#define H1 8
#define C1 8
#define F1 64                    // H1*C1
#define C2 7

#define BSH 6                    // 64 nodes per bucket
#define NB ((N_NODES + 63) / 64) // 1563
#define CAP2 4096                // LDS sorted-edge capacity per bucket (avg ~2111)
#define FB 128                   // partition blocks
#define FCHUNK ((ET + FB - 1) / FB)

typedef __attribute__((ext_vector_type(8))) short short8;
typedef __attribute__((ext_vector_type(4))) float f32x4;

__device__ __forceinline__ unsigned short f2bf(float f) {
    const unsigned u = __float_as_uint(f);
    return (unsigned short)((u + 0x7FFFu + ((u >> 16) & 1u)) >> 16);
}

// ---------------- CSR build: atomic-free 3-phase partition ----------------
__global__ __launch_bounds__(1024) void fill_count(const int* __restrict__ ei,
                                                   int* __restrict__ cntmat) {
    __shared__ int hist[NB];
    const int t = threadIdx.x, blk = blockIdx.x;
    for (int i = t; i < NB; i += 1024) hist[i] = 0;
    __syncthreads();
    const int s0 = blk * FCHUNK;
    const int s1 = min(s0 + FCHUNK, ET);
    for (int i = s0 + t; i < s1; i += 1024) {
        const int dst = (i < N_EDGES) ? ei[N_EDGES + i] : (i - N_EDGES);
        atomicAdd(&hist[dst >> BSH], 1);
    }
    __syncthreads();
    int* row = cntmat + (size_t)blk * NB;
    for (int i = t; i < NB; i += 1024) row[i] = hist[i];
}

__global__ __launch_bounds__(1024) void scan2(const int* __restrict__ cntmat,
                                              int* __restrict__ boff,
                                              int* __restrict__ basemat) {
    __shared__ int tot[2048];
    __shared__ int wsum[16];
    const int t = threadIdx.x;
    const int lane = t & 63;
    const int w = t >> 6;
    for (int b = t; b < 2048; b += 1024) {
        int s = 0;
        if (b < NB)
            for (int j = 0; j < FB; ++j) s += cntmat[(size_t)j * NB + b];
        tot[b] = s;
    }
    __syncthreads();
    int running = 0;
    for (int t0 = 0; t0 < 2048; t0 += 1024) {
        const int v = tot[t0 + t];
        int sc = v;
#pragma unroll
        for (int d = 1; d < 64; d <<= 1) {
            int u = __shfl_up(sc, d);
            if (lane >= d) sc += u;
        }
        if (lane == 63) wsum[w] = sc;
        __syncthreads();
        if (t < 16) {
            int ws = wsum[t];
#pragma unroll
            for (int d = 1; d < 16; d <<= 1) {
                int u = __shfl_up(ws, d);
                if (t >= d) ws += u;
            }
            wsum[t] = ws;
        }
        __syncthreads();
        const int excl = running + (w ? wsum[w - 1] : 0) + sc - v;
        if (t0 + t < NB) boff[t0 + t] = excl;
        const int tt = wsum[15];
        __syncthreads();
        tot[t0 + t] = excl;
        running += tt;
    }
    if (t == 0) boff[NB] = running;     // == ET
    __syncthreads();
    for (int b = t; b < NB; b += 1024) {
        int run = tot[b];
        for (int j = 0; j < FB; ++j) {
            basemat[(size_t)j * NB + b] = run;
            run += cntmat[(size_t)j * NB + b];
        }
    }
}

__global__ __launch_bounds__(1024) void fill_scatter(const int* __restrict__ ei,
                                                     const int* __restrict__ basemat,
                                                     unsigned int* __restrict__ ebuf) {
    __shared__ int cur[NB];
    const int t = threadIdx.x, blk = blockIdx.x;
    const int* row = basemat + (size_t)blk * NB;
    for (int i = t; i < NB; i += 1024) cur[i] = row[i];
    __syncthreads();
    const int s0 = blk * FCHUNK;
    const int s1 = min(s0 + FCHUNK, ET);
    for (int i = s0 + t; i < s1; i += 1024) {
        int src, dst;
        if (i < N_EDGES) { src = ei[i]; dst = ei[N_EDGES + i]; }
        else             { src = dst = i - N_EDGES; }
        const int b = dst >> BSH;
        const int p = atomicAdd(&cur[b], 1);
        ebuf[p] = (unsigned)src | ((unsigned)(dst & 63) << 17);
    }
}

// ---------------- W prep: W1[500][64] -> bf16 fragment-packed wpk ----------------
__global__ __launch_bounds__(256) void wprep(const float* __restrict__ W1,
                                             short* __restrict__ wpk) {
    const int idx = blockIdx.x * 256 + threadIdx.x;
    if (idx >= 32768) return;
    const int j = idx & 7;
    const int l = (idx >> 3) & 63;
    const int f = (idx >> 9) & 3;
    const int ks = idx >> 11;
    const int k = ks * 32 + ((l >> 4) << 3) + j;
    const int col = f * 16 + (l & 15);
    const float fv = (k < F_IN) ? W1[k * F1 + col] : 0.f;
    wpk[idx] = (short)f2bf(fv);
}

// ---------------- layer 1 GEMM: MFMA, split-A (hi+lo) x bf16-W ----------------
__global__ __launch_bounds__(256) void gemm1_kernel(
    const float* __restrict__ x, const short* __restrict__ wpk,
    const float* __restrict__ a_src, const float* __restrict__ a_dst,
    __half* __restrict__ h1, float* __restrict__ as1, float* __restrict__ ad1)
{
    const int t = threadIdx.x;
    const int l = t & 63;
    const int w = t >> 6;
    const int row0 = blockIdx.x * 64 + w * 16;
    const int r = l & 15;
    const int koff = (l >> 4) * 8;
    const float* __restrict__ xp =
        x + (size_t)min(row0 + r, N_NODES - 1) * F_IN + koff;
    const short* __restrict__ wl = wpk + (l << 3);

    f32x4 acc[4];
#pragma unroll
    for (int f = 0; f < 4; ++f) acc[f] = (f32x4){0.f, 0.f, 0.f, 0.f};

    float4 va = *(const float4*)(xp);
    float4 vb = *(const float4*)(xp + 4);
    short8 bcur[4];
#pragma unroll
    for (int f = 0; f < 4; ++f)
        bcur[f] = *(const short8*)(wl + (f << 9));

    for (int ks = 0; ks < 16; ++ks) {
        float v[8];
        v[0] = va.x; v[1] = va.y; v[2] = va.z; v[3] = va.w;
        v[4] = vb.x; v[5] = vb.y; v[6] = vb.z; v[7] = vb.w;
        if (ks < 14) {
            va = *(const float4*)(xp + (ks + 1) * 32);
            vb = *(const float4*)(xp + (ks + 1) * 32 + 4);
        } else if (ks == 14) {
            float tv[8];
#pragma unroll
            for (int j = 0; j < 8; ++j)
                tv[j] = (koff + j < 20) ? xp[480 + j] : 0.f;
            va = make_float4(tv[0], tv[1], tv[2], tv[3]);
            vb = make_float4(tv[4], tv[5], tv[6], tv[7]);
        }
        short8 bnext[4];
        if (ks < 15) {
#pragma unroll
            for (int f = 0; f < 4; ++f)
                bnext[f] = *(const short8*)(wl + (((ks + 1) * 4 + f) << 9));
        }
        short8 ah, al;
#pragma unroll
        for (int j = 0; j < 8; ++j) {
            const unsigned short h = f2bf(v[j]);
            ah[j] = (short)h;
            al[j] = (short)f2bf(v[j] - __uint_as_float((unsigned)h << 16));
        }
#pragma unroll
        for (int f = 0; f < 4; ++f) {
            acc[f] = __builtin_amdgcn_mfma_f32_16x16x32_bf16(ah, bcur[f], acc[f], 0, 0, 0);
            acc[f] = __builtin_amdgcn_mfma_f32_16x16x32_bf16(al, bcur[f], acc[f], 0, 0, 0);
        }
        if (ks < 15) {
#pragma unroll
            for (int f = 0; f < 4; ++f) bcur[f] = bnext[f];
        }
    }

    // epilogue: D[row][col], row = row0 + (l>>4)*4 + reg, col = f*16 + (l&15)
    const int g = l >> 4;
    const int p = r >> 3;
    float asv[4], adv[4];
#pragma unroll
    for (int f = 0; f < 4; ++f) {
        asv[f] = a_src[f * 16 + r];
        adv[f] = a_dst[f * 16 + r];
    }
#pragma unroll
    for (int f = 0; f < 4; ++f) {
#pragma unroll
        for (int reg = 0; reg < 4; ++reg) {
            const int row = row0 + g * 4 + reg;
            const float hv = acc[f][reg];
            if (row < N_NODES)
                h1[(size_t)row * F1 + f * 16 + r] = __float2half(hv);
            float ps = hv * asv[f];
            float pd = hv * adv[f];
            ps += __shfl_xor(ps, 1); ps += __shfl_xor(ps, 2); ps += __shfl_xor(ps, 4);
            pd += __shfl_xor(pd, 1); pd += __shfl_xor(pd, 2); pd += __shfl_xor(pd, 4);
            if ((l & 7) == 0 && row < N_NODES) {
                as1[row * H1 + f * 2 + p] = ps;
                ad1[row * H1 + f * 2 + p] = pd;
            }
        }
    }
}

// ---------------- layer 1 agg: block per bucket, LDS sort + register accum ----
__global__ __launch_bounds__(256) void agg1_kernel(
    const int* __restrict__ boff, const unsigned int* __restrict__ ebuf,
    const __half* __restrict__ h1, const float* __restrict__ as1,
    const float* __restrict__ ad1, const float* __restrict__ b1,
    float* __restrict__ hout)
{
    __shared__ int colb[CAP2];
    __shared__ int hist[64], curs[64], rowp[65];
    const int t = threadIdx.x, b = blockIdx.x;
    const int e0 = boff[b];
    const int cnt = boff[b + 1] - e0;
    const int l = t & 63;
    const int w = t >> 6;
    if (t < 64) hist[t] = 0;
    __syncthreads();

    if (cnt <= CAP2) {
        for (int i = t; i < cnt; i += 256)
            atomicAdd(&hist[ebuf[e0 + i] >> 17], 1);
        __syncthreads();
        if (t < 64) {
            const int v = hist[t];
            int sc = v;
#pragma unroll
            for (int d = 1; d < 64; d <<= 1) {
                int u = __shfl_up(sc, d);
                if (t >= d) sc += u;
            }
            rowp[t] = sc - v;
            curs[t] = sc - v;
            if (t == 63) rowp[64] = sc;
        }
        __syncthreads();
        for (int i = t; i < cnt; i += 256) {
            const unsigned v = ebuf[e0 + i];
            const int p = atomicAdd(&curs[v >> 17], 1);
            colb[p] = (int)(v & 0x1FFFFu);
        }
        __syncthreads();

        const int jsub = l & 7;
        const int hsub = l >> 3;
        const int pbase = l & 56;
        for (int ni = 0; ni < 16; ++ni) {
            const int d = w * 16 + ni;
            const int n = (b << 6) + d;
            if (n >= N_NODES) break;            // wave-uniform
            const int rr0 = rowp[d], rr1 = rowp[d + 1];
            const float adh = ad1[(n << 3) + hsub];
            float den = 0.f, acc = 0.f;
            int j0 = rr0;
            for (; j0 + 8 <= rr1; j0 += 8) {
                const int s_l = colb[j0 + jsub];
                float e = as1[(s_l << 3) + hsub] + adh;
                e = fmaxf(e, 0.2f * e);
                const float p_l = __expf(e);
#pragma unroll
                for (int j = 0; j < 8; ++j) {
                    const float p = __shfl(p_l, pbase + j);
                    const int s_j = __builtin_amdgcn_readlane(s_l, j);
                    const float v = __half2float(h1[((size_t)(unsigned)s_j << 6) + l]);
                    den += p;
                    acc = fmaf(p, v, acc);
                }
            }
            if (j0 < rr1) {
                const int s_l = colb[min(j0 + jsub, rr1 - 1)];
                float e = as1[(s_l << 3) + hsub] + adh;
                e = fmaxf(e, 0.2f * e);
                const float p_l = __expf(e);
#pragma unroll
                for (int j = 0; j < 8; ++j) {
                    if (j0 + j < rr1) {
                        const float p = __shfl(p_l, pbase + j);
                        const int s_j = __builtin_amdgcn_readlane(s_l, j);
                        const float v = __half2float(h1[((size_t)(unsigned)s_j << 6) + l]);
                        den += p;
                        acc = fmaf(p, v, acc);
                    }
                }
            }
            hout[((size_t)n << 6) + l] = acc / den + b1[l];
        }
    } else {
        // fallback (statistically never): predicated full-bucket scan per node
        const int hsub = l >> 3;
        for (int ni = 0; ni < 16; ++ni) {
            const int d = w * 16 + ni;
            const int n = (b << 6) + d;
            if (n >= N_NODES) break;
            const float adh = ad1[(n << 3) + hsub];
            float den = 0.f, acc = 0.f;
            for (int i = 0; i < cnt; ++i) {
                const unsigned v = ebuf[e0 + i];
                if ((int)(v >> 17) == d) {
                    const int s = (int)(v & 0x1FFFFu);
                    float e = as1[(s << 3) + hsub] + adh;
                    e = fmaxf(e, 0.2f * e);
                    const float p = __expf(e);
                    const float hv = __half2float(h1[((size_t)s << 6) + l]);
                    den += p;
                    acc = fmaf(p, hv, acc);
                }
            }
            hout[((size_t)n << 6) + l] = acc / den + b1[l];
        }
    }
}

// ---------------- layer 2 GEMM + attention coefficients ----------------
__global__ __launch_bounds__(256) void gemm2_kernel(
    const float* __restrict__ hin, const float* __restrict__ W2,
    const float* __restrict__ a_src, const float* __restrict__ a_dst,
    float* __restrict__ h2p, float* __restrict__ as2, float* __restrict__ ad2)
{
    __shared__ float w2s[F1 * C2];
    __shared__ float as_s[C2], ad_s[C2];
    for (int i = threadIdx.x; i < F1 * C2; i += blockDim.x) w2s[i] = W2[i];
    if (threadIdx.x < C2) { as_s[threadIdx.x] = a_src[threadIdx.x]; ad_s[threadIdx.x] = a_dst[threadIdx.x]; }
    __syncthreads();

    int n = blockIdx.x * blockDim.x + threadIdx.x;
    if (n >= N_NODES) return;
    float acc[C2];
#pragma unroll
    for (int c = 0; c < C2; ++c) acc[c] = 0.f;
    const float* hp = hin + (size_t)n * F1;
    for (int k = 0; k < F1; k += 4) {
        const float4 hv = *(const float4*)(hp + k);
#pragma unroll
        for (int c = 0; c < C2; ++c) {
            acc[c] = fmaf(hv.x, w2s[(k + 0) * C2 + c], acc[c]);
            acc[c] = fmaf(hv.y, w2s[(k + 1) * C2 + c], acc[c]);
            acc[c] = fmaf(hv.z, w2s[(k + 2) * C2 + c], acc[c]);
            acc[c] = fmaf(hv.w, w2s[(k + 3) * C2 + c], acc[c]);
        }
    }
    float s = 0.f, d = 0.f;
#pragma unroll
    for (int c = 0; c < C2; ++c) {
        s = fmaf(acc[c], as_s[c], s);
        d = fmaf(acc[c], ad_s[c], d);
    }
    float4* o = (float4*)(h2p + (size_t)n * 8);
    o[0] = make_float4(acc[0], acc[1], acc[2], acc[3]);
    o[1] = make_float4(acc[4], acc[5], acc[6], 0.f);
    as2[n] = s;
    ad2[n] = d;
}

// ---------------- layer 2 agg: block per bucket, LDS sort + quarter-wave ----
__global__ __launch_bounds__(256) void agg2_kernel(
    const int* __restrict__ boff, const unsigned int* __restrict__ ebuf,
    const float* __restrict__ h2p, const float* __restrict__ as2,
    const float* __restrict__ ad2, const float* __restrict__ b2,
    float* __restrict__ out)
{
    __shared__ int colb[CAP2];
    __shared__ int hist[64], curs[64], rowp[65];
    const int t = threadIdx.x, b = blockIdx.x;
    const int e0 = boff[b];
    const int cnt = boff[b + 1] - e0;
    if (t < 64) hist[t] = 0;
    __syncthreads();

    const int d = t >> 2;             // node-in-bucket
    const int q = t & 3;
    const int n = (b << 6) + d;

    if (cnt <= CAP2) {
        for (int i = t; i < cnt; i += 256)
            atomicAdd(&hist[ebuf[e0 + i] >> 17], 1);
        __syncthreads();
        if (t < 64) {
            const int v = hist[t];
            int sc = v;
#pragma unroll
            for (int dd = 1; dd < 64; dd <<= 1) {
                int u = __shfl_up(sc, dd);
                if (t >= dd) sc += u;
            }
            rowp[t] = sc - v;
            curs[t] = sc - v;
            if (t == 63) rowp[64] = sc;
        }
        __syncthreads();
        for (int i = t; i < cnt; i += 256) {
            const unsigned v = ebuf[e0 + i];
            const int p = atomicAdd(&curs[v >> 17], 1);
            colb[p] = (int)(v & 0x1FFFFu);
        }
        __syncthreads();

        if (n >= N_NODES) return;
        const int rr0 = rowp[d], rr1 = rowp[d + 1];
        const float adn = ad2[n];
        float denom = 0.f;
        float a0 = 0, a1 = 0, a2 = 0, a3 = 0, a4 = 0, a5 = 0, a6 = 0;
        for (int j = rr0 + q; j < rr1; j += 4) {
            const int s = colb[j];
            float e = as2[s] + adn;
            e = fmaxf(e, 0.2f * e);
            const float ex = __expf(e);
            const float4 va = *(const float4*)(h2p + (size_t)s * 8);
            const float4 vb = *(const float4*)(h2p + (size_t)s * 8 + 4);
            denom += ex;
            a0 = fmaf(ex, va.x, a0); a1 = fmaf(ex, va.y, a1);
            a2 = fmaf(ex, va.z, a2); a3 = fmaf(ex, va.w, a3);
            a4 = fmaf(ex, vb.x, a4); a5 = fmaf(ex, vb.y, a5);
            a6 = fmaf(ex, vb.z, a6);
        }
#pragma unroll
        for (int dd = 1; dd < 4; dd <<= 1) {
            denom += __shfl_xor(denom, dd);
            a0 += __shfl_xor(a0, dd); a1 += __shfl_xor(a1, dd);
            a2 += __shfl_xor(a2, dd); a3 += __shfl_xor(a3, dd);
            a4 += __shfl_xor(a4, dd); a5 += __shfl_xor(a5, dd);
            a6 += __shfl_xor(a6, dd);
        }
        const float inv = 1.f / denom;
        float v0 = a0 * inv + b2[0], v1 = a1 * inv + b2[1];
        float v2 = a2 * inv + b2[2], v3 = a3 * inv + b2[3];
        float v4 = a4 * inv + b2[4], v5 = a5 * inv + b2[5];
        float v6 = a6 * inv + b2[6];
        float mx = fmaxf(fmaxf(fmaxf(v0, v1), fmaxf(v2, v3)), fmaxf(fmaxf(v4, v5), v6));
        const float se = __expf(v0 - mx) + __expf(v1 - mx) + __expf(v2 - mx) +
                         __expf(v3 - mx) + __expf(v4 - mx) + __expf(v5 - mx) +
                         __expf(v6 - mx);
        const float lse = __logf(se) + mx;
        const float wa = (q == 0) ? v0 : (q == 1) ? v1 : (q == 2) ? v2 : v3;
        const float wb = (q == 0) ? v4 : (q == 1) ? v5 : v6;
        out[n * C2 + q] = wa - lse;
        if (q < 3) out[n * C2 + q + 4] = wb - lse;
    } else {
        // fallback (statistically never): predicated full-bucket scan
        if (n >= N_NODES) return;
        const float adn = ad2[n];
        float denom = 0.f;
        float a0 = 0, a1 = 0, a2 = 0, a3 = 0, a4 = 0, a5 = 0, a6 = 0;
        for (int i = q; i < cnt; i += 4) {
            const unsigned v = ebuf[e0 + i];
            if ((int)(v >> 17) == d) {
                const int s = (int)(v & 0x1FFFFu);
                float e = as2[s] + adn;
                e = fmaxf(e, 0.2f * e);
                const float ex = __expf(e);
                const float4 va = *(const float4*)(h2p + (size_t)s * 8);
                const float4 vb = *(const float4*)(h2p + (size_t)s * 8 + 4);
                denom += ex;
                a0 = fmaf(ex, va.x, a0); a1 = fmaf(ex, va.y, a1);
                a2 = fmaf(ex, va.z, a2); a3 = fmaf(ex, va.w, a3);
                a4 = fmaf(ex, vb.x, a4); a5 = fmaf(ex, vb.y, a5);
                a6 = fmaf(ex, vb.z, a6);
            }
        }
#pragma unroll
        for (int dd = 1; dd < 4; dd <<= 1) {
            denom += __shfl_xor(denom, dd);
            a0 += __shfl_xor(a0, dd); a1 += __shfl_xor(a1, dd);
            a2 += __shfl_xor(a2, dd); a3 += __shfl_xor(a3, dd);
            a4 += __shfl_xor(a4, dd); a5 += __shfl_xor(a5, dd);
            a6 += __shfl_xor(a6, dd);
        }
        const float inv = 1.f / denom;
        float v0 = a0 * inv + b2[0], v1 = a1 * inv + b2[1];
        float v2 = a2 * inv + b2[2], v3 = a3 * inv + b2[3];
        float v4 = a4 * inv + b2[4], v5 = a5 * inv + b2[5];
        float v6 = a6 * inv + b2[6];
        float mx = fmaxf(fmaxf(fmaxf(v0, v1), fmaxf(v2, v3)), fmaxf(fmaxf(v4, v5), v6));
        const float se = __expf(v0 - mx) + __expf(v1 - mx) + __expf(v2 - mx) +
                         __expf(v3 - mx) + __expf(v4 - mx) + __expf(v5 - mx) +
                         __expf(v6 - mx);
        const float lse = __logf(se) + mx;
        const float wa = (q == 0) ? v0 : (q == 1) ? v1 : (q == 2) ? v2 : v3;
        const float wb = (q == 0) ? v4 : (q == 1) ? v5 : v6;
        out[n * C2 + q] = wa - lse;
        if (q < 3) out[n * C2 + q + 4] = wb - lse;
    }
}

extern "C" void kernel_launch(void* const* d_in, const int* in_sizes, int n_in,
                              void* d_out, int out_size, void* d_ws, size_t ws_size,
                              hipStream_t stream) {
    const float* x      = (const float*)d_in[0];
    const int*   ei     = (const int*)  d_in[1];
    const float* W1     = (const float*)d_in[2];
    const float* a_src1 = (const float*)d_in[3];
    const float* a_dst1 = (const float*)d_in[4];
    const float* b1     = (const float*)d_in[5];
    const float* W2     = (const float*)d_in[6];
    const float* a_src2 = (const float*)d_in[7];
    const float* a_dst2 = (const float*)d_in[8];
    const float* b2     = (const float*)d_in[9];
    float* out = (float*)d_out;

    char* ws = (char*)d_ws;
    size_t off = 0;
    auto alloc = [&](size_t bytes) -> void* {
        void* p = ws + off;
        off += (bytes + 255) & ~(size_t)255;
        return p;
    };
    int*          boff    = (int*)   alloc((size_t)(NB + 1) * sizeof(int));
    int*          cntmat  = (int*)   alloc((size_t)FB * NB * sizeof(int));
    int*          basemat = (int*)   alloc((size_t)FB * NB * sizeof(int));
    unsigned int* ebuf    = (unsigned int*)alloc((size_t)ET * sizeof(unsigned int));
    short*        wpk     = (short*) alloc((size_t)32768 * sizeof(short));
    __half*       h1      = (__half*)alloc((size_t)N_NODES * F1 * sizeof(__half));
    float*        as1     = (float*) alloc((size_t)N_NODES * H1 * sizeof(float));
    float*        ad1     = (float*) alloc((size_t)N_NODES * H1 * sizeof(float));
    float*        hout1   = (float*) alloc((size_t)N_NODES * F1 * sizeof(float));
    float*        h2p     = (float*) alloc((size_t)N_NODES * 8 * sizeof(float));
    float*        as2     = (float*) alloc((size_t)N_NODES * sizeof(float));
    float*        ad2     = (float*) alloc((size_t)N_NODES * sizeof(float));

    wprep<<<128, 256, 0, stream>>>(W1, wpk);
    fill_count<<<FB, 1024, 0, stream>>>(ei, cntmat);
    scan2<<<1, 1024, 0, stream>>>(cntmat, boff, basemat);
    fill_scatter<<<FB, 1024, 0, stream>>>(ei, basemat, ebuf);
    gemm1_kernel<<<(N_NODES + 63) / 64, 256, 0, stream>>>(x, wpk, a_src1, a_dst1, h1, as1, ad1);
    agg1_kernel<<<NB, 256, 0, stream>>>(boff, ebuf, h1, as1, ad1, b1, hout1);
    gemm2_kernel<<<(N_NODES + 255) / 256, 256, 0, stream>>>(hout1, W2, a_src2, a_dst2, h2p, as2, ad2);
    agg2_kernel<<<NB, 256, 0, stream>>>(boff, ebuf, h2p, as2, ad2, b2, out);
}